// Round 8
// baseline (128.326 us; speedup 1.0000x reference)
//
#include <hip/hip_runtime.h>
#include <math.h>

#define L_SEQ 1024
#define TOPK 6
#define SSTR 1057   // per-seq LDS plane stride (floats): 32*33+1, odd -> bank skew

// ---------------------------------------------------------------------------
// Kernel 1: packed complex FFT + cross-spectrum partials.
// Per block: 8 sequences z = q[b,:,h,e] + i*k[b,:,h,e] (e = e0..e0+7).
// 1024-pt FFT via four-step: FFT32 over n2 (per n1) -> twiddle W1024^{n1 k2}
// -> FFT32 over n1 (per k2). Real-split pairing gives
//   S[j] = Qf[j]*conj(Kf[j]) = 0.5*Im(A*P) + i*0.25*(|A|^2-|P|^2),
//   A = Z[j], P = Z[1024-j].
// Block-reduced over 8 seqs -> partial[bid][2048] (Re 0..1023, Im 1024..2047).
// ---------------------------------------------------------------------------
#define FFTSTAGE(M, H, SH)                                                \
  _Pragma("unroll")                                                       \
  for (int k_ = 0; k_ < 32; k_ += (M)) {                                  \
    _Pragma("unroll")                                                     \
    for (int t_ = 0; t_ < (H); ++t_) {                                    \
      const float2 w_ = twc[t_ << (SH)];                                  \
      const int a_ = k_ + t_, b_ = a_ + (H);                              \
      const float vr_ = zr[b_] * w_.x - zi[b_] * w_.y;                    \
      const float vi_ = zr[b_] * w_.y + zi[b_] * w_.x;                    \
      zr[b_] = zr[a_] - vr_; zi[b_] = zi[a_] - vi_;                       \
      zr[a_] += vr_;         zi[a_] += vi_;                               \
    }                                                                     \
  }

__global__ __launch_bounds__(256) void fft_spec_kernel(
    const float* __restrict__ q, const float* __restrict__ k,
    float* __restrict__ partial)
{
  __shared__ float pr[8 * SSTR];
  __shared__ float pim[8 * SSTR];
  __shared__ float2 twc[1024];

  const int tid = threadIdx.x;

  // XCD-chunked swizzle: consecutive work ids stay on one XCD (L2 line share)
  const int bid  = blockIdx.x;                 // 0..2047
  const int work = (bid & 7) * 256 + (bid >> 3);
  const int e0 = (work & 7) * 8;
  const int h  = (work >> 3) & 7;
  const int b  = work >> 6;

  // twiddle table: twc[m] = e^{-2*pi*i*m/1024}
  #pragma unroll
  for (int u = 0; u < 4; ++u) {
    const int m = u * 256 + tid;
    float s_, c_;
    sincosf((float)m * 6.13592315e-03f, &s_, &c_);
    twc[m] = make_float2(c_, -s_);
  }

  // stage: element l of seq s stored at plane[s*SSTR + (l&31)*33 + (l>>5)]
  {
    const float* qb = q + (size_t)b * 524288 + h * 64 + e0;
    const float* kb = k + (size_t)b * 524288 + h * 64 + e0;
    const int ep = (tid & 3) * 2;
    const int lb = tid >> 2;          // 0..63
    #pragma unroll
    for (int it = 0; it < 16; ++it) {
      const int l = it * 64 + lb;
      const float2 qv = *(const float2*)(qb + l * 512 + ep);
      const float2 kv = *(const float2*)(kb + l * 512 + ep);
      const int col = (l & 31) * 33 + (l >> 5);
      pr[(ep + 0) * SSTR + col] = qv.x;
      pr[(ep + 1) * SSTR + col] = qv.y;
      pim[(ep + 0) * SSTR + col] = kv.x;
      pim[(ep + 1) * SSTR + col] = kv.y;
    }
  }
  __syncthreads();

  const int s = tid >> 5;     // group = sequence
  const int i = tid & 31;     // lane within group
  const int BR[32] = {0,16,8,24,4,20,12,28,2,18,10,26,6,22,14,30,
                      1,17,9,25,5,21,13,29,3,19,11,27,7,23,15,31};
  float zr[32], zi[32];

  // ---- phase 1: FFT32 over n2 for fixed n1 = i ----
  {
    const int rowbase = s * SSTR + i * 33;
    #pragma unroll
    for (int p = 0; p < 32; ++p) {
      zr[p] = pr[rowbase + BR[p]];
      zi[p] = pim[rowbase + BR[p]];
    }
    FFTSTAGE(2, 1, 9) FFTSTAGE(4, 2, 8) FFTSTAGE(8, 4, 7)
    FFTSTAGE(16, 8, 6) FFTSTAGE(32, 16, 5)
    // twiddle W1024^{i*k2} via recurrence; write back in place
    const float2 wstep = twc[i];
    float wr = 1.f, wi = 0.f;
    #pragma unroll
    for (int k2 = 0; k2 < 32; ++k2) {
      pr[rowbase + k2]  = zr[k2] * wr - zi[k2] * wi;
      pim[rowbase + k2] = zr[k2] * wi + zi[k2] * wr;
      const float nwr = wr * wstep.x - wi * wstep.y;
      wi = wr * wstep.y + wi * wstep.x;
      wr = nwr;
    }
  }
  __syncthreads();

  // ---- phase 2: FFT32 over n1 for fixed k2 = i ----
  const int j = i;
  #pragma unroll
  for (int p = 0; p < 32; ++p) {
    zr[p] = pr[s * SSTR + BR[p] * 33 + j];
    zi[p] = pim[s * SSTR + BR[p] * 33 + j];
  }
  __syncthreads();            // all column reads done before row writes
  FFTSTAGE(2, 1, 9) FFTSTAGE(4, 2, 8) FFTSTAGE(8, 4, 7)
  FFTSTAGE(16, 8, 6) FFTSTAGE(32, 16, 5)
  // z[k1] = Z[32*k1 + j]; publish rows for pairing
  #pragma unroll
  for (int k1 = 0; k1 < 32; ++k1) {
    pr[s * SSTR + j * 33 + k1]  = zr[k1];
    pim[s * SSTR + j * 33 + k1] = zi[k1];
  }
  __syncthreads();

  // ---- pairing: S[32k1+j] from A=Z[jbin], P=Z[1024-jbin] ----
  {
    const int prow = (32 - j) & 31;
    #pragma unroll
    for (int k1 = 0; k1 < 32; ++k1) {
      const int pcol = j ? (31 - k1) : ((32 - k1) & 31);
      const float prr = pr[s * SSTR + prow * 33 + pcol];
      const float pii = pim[s * SSTR + prow * 33 + pcol];
      const float ar = zr[k1], ai = zi[k1];
      zr[k1] = 0.5f * (ar * pii + ai * prr);                      // Re S
      zi[k1] = 0.25f * (ar * ar + ai * ai - prr * prr - pii * pii); // Im S
    }
  }
  __syncthreads();            // all pairing reads done before overwrite
  #pragma unroll
  for (int k1 = 0; k1 < 32; ++k1) {
    pr[s * SSTR + j * 33 + k1]  = zr[k1];
    pim[s * SSTR + j * 33 + k1] = zi[k1];
  }
  __syncthreads();

  // ---- reduce 8 seqs -> per-block partial spectrum ----
  #pragma unroll
  for (int u = 0; u < 4; ++u) {
    const int bin = u * 256 + tid;
    const int jj = bin & 31, kk = bin >> 5;
    float sr = 0.f, si = 0.f;
    #pragma unroll
    for (int s2 = 0; s2 < 8; ++s2) {
      sr += pr[s2 * SSTR + jj * 33 + kk];
      si += pim[s2 * SSTR + jj * 33 + kk];
    }
    partial[(size_t)bid * 2048 + bin] = sr;
    partial[(size_t)bid * 2048 + 1024 + bin] = si;
  }
}

// ---------------------------------------------------------------------------
// Kernel 2a/2b: two-stage reduction of 2048 partial spectra -> S[2048]
// ---------------------------------------------------------------------------
__global__ __launch_bounds__(256) void spec_reduce_a(
    const float* __restrict__ partial, float* __restrict__ partial2)
{
  const int v = (blockIdx.x & 7) * 256 + threadIdx.x;   // 0..2047
  const int rc = blockIdx.x >> 3;                       // 0..7
  float acc = 0.f;
  #pragma unroll 8
  for (int r = rc * 256; r < rc * 256 + 256; ++r)
    acc += partial[(size_t)r * 2048 + v];
  partial2[(size_t)rc * 2048 + v] = acc;
}

__global__ __launch_bounds__(256) void spec_reduce_b(
    const float* __restrict__ partial2, float* __restrict__ S)
{
  const int v = blockIdx.x * 256 + threadIdx.x;
  float acc = 0.f;
  #pragma unroll
  for (int rc = 0; rc < 8; ++rc) acc += partial2[(size_t)rc * 2048 + v];
  S[v] = acc;
}

// ---------------------------------------------------------------------------
// Kernel 3: c[tau] = (1/(1024*16384)) * sum_j Re(S[j] * e^{+2pi i j tau/1024})
// ---------------------------------------------------------------------------
__global__ __launch_bounds__(256) void corr_kernel(
    const float* __restrict__ S, float* __restrict__ c)
{
  __shared__ float2 twc[1024];
  __shared__ float sm[256];
  const int t = threadIdx.x;
  #pragma unroll
  for (int u = 0; u < 4; ++u) {
    const int m = u * 256 + t;
    float s_, c_;
    sincosf((float)m * 6.13592315e-03f, &s_, &c_);
    twc[m] = make_float2(c_, -s_);   // e^{-i theta}; Re(S e^{+i}) = SR*x + SI*y
  }
  __syncthreads();
  const int tau = blockIdx.x * 64 + (t & 63);
  const int jc = t >> 6;
  float acc = 0.f;
  for (int jj = 0; jj < 256; ++jj) {
    const int j = jc * 256 + jj;
    const float2 w = twc[(j * tau) & 1023];
    acc += S[j] * w.x + S[1024 + j] * w.y;
  }
  sm[t] = acc;
  __syncthreads();
  if (t < 64)
    c[blockIdx.x * 64 + t] =
        (sm[t] + sm[64 + t] + sm[128 + t] + sm[192 + t]) * (1.0f / 16777216.0f);
}

// ---------------------------------------------------------------------------
// Kernel 4: top-6 (desc, smaller-index tie-break) + softmax. 1 block.
// ---------------------------------------------------------------------------
__global__ __launch_bounds__(256) void topk_kernel(
    const float* __restrict__ c, int* __restrict__ idx_out,
    float* __restrict__ w_out)
{
  __shared__ float vals[L_SEQ];
  __shared__ float rv[256];
  __shared__ int ri[256];
  __shared__ float topv[TOPK];
  __shared__ int topi[TOPK];
  const int tid = threadIdx.x;
  for (int i = tid; i < L_SEQ; i += 256) vals[i] = c[i];
  __syncthreads();

  for (int kk = 0; kk < TOPK; ++kk) {
    float bv = -INFINITY;
    int bi = 1 << 30;
    for (int i = tid; i < L_SEQ; i += 256) {
      const float v = vals[i];
      if (v > bv || (v == bv && i < bi)) { bv = v; bi = i; }
    }
    rv[tid] = bv; ri[tid] = bi;
    __syncthreads();
    for (int off = 128; off > 0; off >>= 1) {
      if (tid < off) {
        const float v2 = rv[tid + off];
        const int i2 = ri[tid + off];
        if (v2 > rv[tid] || (v2 == rv[tid] && i2 < ri[tid])) {
          rv[tid] = v2; ri[tid] = i2;
        }
      }
      __syncthreads();
    }
    if (tid == 0) {
      topv[kk] = rv[0];
      topi[kk] = ri[0];
      vals[ri[0]] = -INFINITY;
    }
    __syncthreads();
  }

  if (tid == 0) {
    const float m = topv[0];
    float e[TOPK], sum = 0.f;
    for (int i = 0; i < TOPK; ++i) { e[i] = expf(topv[i] - m); sum += e[i]; }
    const float inv = 1.0f / sum;
    for (int i = 0; i < TOPK; ++i) { w_out[i] = e[i] * inv; idx_out[i] = topi[i]; }
  }
}

// ---------------------------------------------------------------------------
// Kernel 5: out[b,l,h,e] = sum_k w[k] * v[b,(l+idx[k])%L,h,e]
// ---------------------------------------------------------------------------
__global__ __launch_bounds__(256) void agg_kernel(
    const float* __restrict__ v, const int* __restrict__ idx,
    const float* __restrict__ w, float4* __restrict__ out)
{
  __shared__ int sidx[TOPK];
  __shared__ float sw[TOPK];
  if (threadIdx.x < TOPK) {
    sidx[threadIdx.x] = idx[threadIdx.x];
    sw[threadIdx.x] = w[threadIdx.x];
  }
  __syncthreads();

  const int i = blockIdx.x * 256 + threadIdx.x;   // 0 .. 2^22-1
  const int he4 = i & 127;
  const int l = (i >> 7) & (L_SEQ - 1);
  const int b = i >> 17;
  const float4* vb = (const float4*)v + (size_t)b * (L_SEQ * 128);

  float4 acc = make_float4(0.f, 0.f, 0.f, 0.f);
  #pragma unroll
  for (int kk = 0; kk < TOPK; ++kk) {
    const int src = (l + sidx[kk]) & (L_SEQ - 1);
    const float4 vv = vb[(size_t)src * 128 + he4];
    const float wk = sw[kk];
    acc.x += wk * vv.x; acc.y += wk * vv.y;
    acc.z += wk * vv.z; acc.w += wk * vv.w;
  }
  out[i] = acc;
}

// ---------------------------------------------------------------------------
extern "C" void kernel_launch(void* const* d_in, const int* in_sizes, int n_in,
                              void* d_out, int out_size, void* d_ws, size_t ws_size,
                              hipStream_t stream) {
  const float* q = (const float*)d_in[0];
  const float* k = (const float*)d_in[1];
  const float* v = (const float*)d_in[2];
  // d_in[3] = attn_mask (scalar 0) -- unused

  float* out = (float*)d_out;
  // scratch inside d_out (consumed before agg overwrites):
  //   partial : 2048 x 2048 floats (16 MB) at out[0]
  //   partial2:    8 x 2048 floats (64 KB) right after
  float* partial  = out;
  float* partial2 = out + (size_t)2048 * 2048;

  float* c    = (float*)d_ws;                          // 1024 floats
  int*   idxp = (int*)((char*)d_ws + 4096);            // 6 ints
  float* wp   = (float*)((char*)d_ws + 4096 + 64);     // 6 floats
  float* S    = (float*)((char*)d_ws + 8192);          // 2048 floats

  fft_spec_kernel<<<2048, 256, 0, stream>>>(q, k, partial);
  spec_reduce_a<<<64, 256, 0, stream>>>(partial, partial2);
  spec_reduce_b<<<8, 256, 0, stream>>>(partial2, S);
  corr_kernel<<<16, 256, 0, stream>>>(S, c);
  topk_kernel<<<1, 256, 0, stream>>>(c, idxp, wp);
  agg_kernel<<<(L_SEQ * 32 * 128) / 256, 256, 0, stream>>>(v, idxp, wp,
                                                           (float4*)out);
}